// Round 3
// baseline (269.055 us; speedup 1.0000x reference)
//
#include <hip/hip_runtime.h>

#define EPS 1e-5f

constexpr int F    = 256;        // features
constexpr int F4   = 64;         // float4 per row
constexpr int ROWS = 32 * 4096;  // 131072 rows
constexpr int NG   = ROWS / 16;  // 8192 groups of 16 rows (4 waves x 4 rows)

// ---------------------------------------------------------------------------
// Pass 1: per-feature partial sums over masked rows.
// 2048 blocks (8 blocks/CU -> 32 waves/CU, full occupancy for latency hiding).
// Each wave: 4 consecutive rows/iter, one int4 mask load, up to 4 independent
// float4 x-loads in flight. Wave-uniform branches -> no divergence.
// Partials column-major pS[f*nblk + b] so finalize reads coalesced.
// ---------------------------------------------------------------------------
__global__ void __launch_bounds__(256) reduce_kernel(
    const float4* __restrict__ x4, const int4* __restrict__ mask4,
    float* __restrict__ pS1, float* __restrict__ pS2,
    float* __restrict__ pCnt, int nblk)
{
    const int lane = threadIdx.x & 63;
    const int wv   = threadIdx.x >> 6;

    float4 s1 = {0.f, 0.f, 0.f, 0.f};
    float4 s2 = {0.f, 0.f, 0.f, 0.f};
    float  cnt = 0.f;

    for (int g = blockIdx.x; g < NG; g += nblk) {
        const int row0 = g * 16 + wv * 4;
        const int4 m = mask4[row0 >> 2];                 // wave-uniform 16B load
        const float4* p = x4 + (size_t)row0 * F4 + lane;
        if (m.x > 0) { const float4 v = p[0];
            s1.x += v.x; s1.y += v.y; s1.z += v.z; s1.w += v.w;
            s2.x = fmaf(v.x,v.x,s2.x); s2.y = fmaf(v.y,v.y,s2.y);
            s2.z = fmaf(v.z,v.z,s2.z); s2.w = fmaf(v.w,v.w,s2.w); cnt += 1.f; }
        if (m.y > 0) { const float4 v = p[F4];
            s1.x += v.x; s1.y += v.y; s1.z += v.z; s1.w += v.w;
            s2.x = fmaf(v.x,v.x,s2.x); s2.y = fmaf(v.y,v.y,s2.y);
            s2.z = fmaf(v.z,v.z,s2.z); s2.w = fmaf(v.w,v.w,s2.w); cnt += 1.f; }
        if (m.z > 0) { const float4 v = p[2 * F4];
            s1.x += v.x; s1.y += v.y; s1.z += v.z; s1.w += v.w;
            s2.x = fmaf(v.x,v.x,s2.x); s2.y = fmaf(v.y,v.y,s2.y);
            s2.z = fmaf(v.z,v.z,s2.z); s2.w = fmaf(v.w,v.w,s2.w); cnt += 1.f; }
        if (m.w > 0) { const float4 v = p[3 * F4];
            s1.x += v.x; s1.y += v.y; s1.z += v.z; s1.w += v.w;
            s2.x = fmaf(v.x,v.x,s2.x); s2.y = fmaf(v.y,v.y,s2.y);
            s2.z = fmaf(v.z,v.z,s2.z); s2.w = fmaf(v.w,v.w,s2.w); cnt += 1.f; }
    }

    __shared__ float4 sh1[256];
    __shared__ float4 sh2[256];
    __shared__ float  shc[4];
    sh1[threadIdx.x] = s1;
    sh2[threadIdx.x] = s2;
    if (lane == 0) shc[wv] = cnt;            // cnt is wave-uniform
    __syncthreads();

    if (wv == 0) {
        float4 a = sh1[lane];
        float4 b = sh2[lane];
        #pragma unroll
        for (int w = 1; w < 4; ++w) {
            const float4 c = sh1[w * 64 + lane];
            const float4 d = sh2[w * 64 + lane];
            a.x += c.x; a.y += c.y; a.z += c.z; a.w += c.w;
            b.x += d.x; b.y += d.y; b.z += d.z; b.w += d.w;
        }
        const int f0  = lane * 4;
        const int blk = blockIdx.x;
        pS1[(size_t)(f0 + 0) * nblk + blk] = a.x;
        pS1[(size_t)(f0 + 1) * nblk + blk] = a.y;
        pS1[(size_t)(f0 + 2) * nblk + blk] = a.z;
        pS1[(size_t)(f0 + 3) * nblk + blk] = a.w;
        pS2[(size_t)(f0 + 0) * nblk + blk] = b.x;
        pS2[(size_t)(f0 + 1) * nblk + blk] = b.y;
        pS2[(size_t)(f0 + 2) * nblk + blk] = b.z;
        pS2[(size_t)(f0 + 3) * nblk + blk] = b.w;
        if (lane == 0)
            pCnt[blk] = shc[0] + shc[1] + shc[2] + shc[3];
    }
}

// ---------------------------------------------------------------------------
// Pass 2: fold partials -> scale/shift. One block per feature, 64 threads
// strided over the column (coalesced: column-major layout), shuffle-reduce.
// ---------------------------------------------------------------------------
__global__ void __launch_bounds__(64) finalize_kernel(
    const float* __restrict__ pS1, const float* __restrict__ pS2,
    const float* __restrict__ pCnt,
    const float* __restrict__ gamma, const float* __restrict__ beta,
    float* __restrict__ scale, float* __restrict__ shift, int nblk)
{
    const int f = blockIdx.x;
    const int t = threadIdx.x;

    const float* c1 = pS1 + (size_t)f * nblk;
    const float* c2 = pS2 + (size_t)f * nblk;

    float s1 = 0.f, s2 = 0.f, c = 0.f;
    for (int b = t; b < nblk; b += 64) {
        s1 += c1[b];
        s2 += c2[b];
        c  += pCnt[b];
    }
    #pragma unroll
    for (int off = 32; off > 0; off >>= 1) {
        s1 += __shfl_down(s1, off);
        s2 += __shfl_down(s2, off);
        c  += __shfl_down(c,  off);
    }
    if (t == 0) {
        const float inv_cnt = 1.f / c;
        const float mean = s1 * inv_cnt;
        const float var  = fmaf(-mean, mean, s2 * inv_cnt);
        const float inv  = rsqrtf(var + EPS);
        const float g    = gamma[f] * inv;
        scale[f] = g;
        shift[f] = fmaf(-mean, g, beta[f]);
    }
}

// ---------------------------------------------------------------------------
// Pass 3: out = mask ? x*scale + shift : x
// Branchless: 4 consecutive rows per wave, all loads/stores unconditional
// (4 in flight), per-element select via cndmask. 2048 blocks = 32 waves/CU.
// ---------------------------------------------------------------------------
__device__ __forceinline__ float4 sel4(int m, const float4 v,
                                       const float4 sc, const float4 sh)
{
    float4 o;
    o.x = (m > 0) ? fmaf(v.x, sc.x, sh.x) : v.x;
    o.y = (m > 0) ? fmaf(v.y, sc.y, sh.y) : v.y;
    o.z = (m > 0) ? fmaf(v.z, sc.z, sh.z) : v.z;
    o.w = (m > 0) ? fmaf(v.w, sc.w, sh.w) : v.w;
    return o;
}

__global__ void __launch_bounds__(256) norm_kernel(
    const float4* __restrict__ x4, const int4* __restrict__ mask4,
    const float4* __restrict__ scale4, const float4* __restrict__ shift4,
    float4* __restrict__ out4)
{
    const int lane = threadIdx.x & 63;
    const int wv   = threadIdx.x >> 6;
    const float4 sc = scale4[lane];
    const float4 sh = shift4[lane];

    for (int g = blockIdx.x; g < NG; g += gridDim.x) {
        const int row0 = g * 16 + wv * 4;
        const int4 m = mask4[row0 >> 2];
        const size_t base = (size_t)row0 * F4 + lane;
        const float4 v0 = x4[base];
        const float4 v1 = x4[base + F4];
        const float4 v2 = x4[base + 2 * F4];
        const float4 v3 = x4[base + 3 * F4];
        out4[base]          = sel4(m.x, v0, sc, sh);
        out4[base + F4]     = sel4(m.y, v1, sc, sh);
        out4[base + 2 * F4] = sel4(m.z, v2, sc, sh);
        out4[base + 3 * F4] = sel4(m.w, v3, sc, sh);
    }
}

// ---------------------------------------------------------------------------
extern "C" void kernel_launch(void* const* d_in, const int* in_sizes, int n_in,
                              void* d_out, int out_size, void* d_ws, size_t ws_size,
                              hipStream_t stream)
{
    const float* x     = (const float*)d_in[0];
    const int*   mask  = (const int*)d_in[1];
    const float* gamma = (const float*)d_in[2];
    const float* beta  = (const float*)d_in[3];
    float* out = (float*)d_out;
    float* ws  = (float*)d_ws;

    // ws layout: pS1[F*nblk] | pS2[F*nblk] | pCnt[nblk] | scale[256] | shift[256]
    // nblk=2048 -> 8 blocks/CU (32 waves/CU) in the reduce pass. ~4.2 MiB ws.
    int nblk = 2048;
    while (nblk > 4 &&
           ((size_t)nblk * F * 2 + nblk + 512) * sizeof(float) > ws_size)
        nblk >>= 1;

    float* pS1   = ws;
    float* pS2   = pS1 + (size_t)F * nblk;
    float* pCnt  = pS2 + (size_t)F * nblk;
    float* scale = pCnt + nblk;
    float* shift = scale + F;

    reduce_kernel<<<nblk, 256, 0, stream>>>(
        (const float4*)x, (const int4*)mask, pS1, pS2, pCnt, nblk);
    finalize_kernel<<<F, 64, 0, stream>>>(
        pS1, pS2, pCnt, gamma, beta, scale, shift, nblk);
    norm_kernel<<<2048, 256, 0, stream>>>(
        (const float4*)x, (const int4*)mask, (const float4*)scale,
        (const float4*)shift, (float4*)out);
}

// Round 5
// 252.462 us; speedup vs baseline: 1.0657x; 1.0657x over previous
//
#include <hip/hip_runtime.h>

#define EPS 1e-5f

constexpr int F    = 256;        // features
constexpr int F4   = 64;         // float4 per row
constexpr int ROWS = 32 * 4096;  // 131072 rows
constexpr int NG   = ROWS / 32;  // 4096 groups of 32 rows (4 waves x 8 rows)

// native vector type for nontemporal builtin (HIP float4 is a class)
typedef float vfloat4 __attribute__((ext_vector_type(4)));

// ---------------------------------------------------------------------------
// Pass 1: per-feature partial sums over masked rows.
// 8 consecutive rows per wave per iter: two wave-uniform int4 mask loads,
// then ALL masked x-loads issued back-to-back (up to 8 KiB in flight per
// wave) before any accumulation -> deep vmcnt pipelining. Wave-uniform
// branches, no divergence. Partials column-major pS[f*nblk + b].
// ---------------------------------------------------------------------------
__global__ void __launch_bounds__(256, 4) reduce_kernel(
    const float4* __restrict__ x4, const int4* __restrict__ mask4,
    float* __restrict__ pS1, float* __restrict__ pS2,
    float* __restrict__ pCnt, int nblk)
{
    const int lane = threadIdx.x & 63;
    const int wv   = threadIdx.x >> 6;

    float4 s1 = {0.f, 0.f, 0.f, 0.f};
    float4 s2 = {0.f, 0.f, 0.f, 0.f};
    float  cnt = 0.f;

    for (int g = blockIdx.x; g < NG; g += nblk) {
        const int row0 = g * 32 + wv * 8;
        const int4 mlo = mask4[(row0 >> 2) + 0];   // rows row0..row0+3
        const int4 mhi = mask4[(row0 >> 2) + 1];   // rows row0+4..row0+7
        const int m[8] = {mlo.x, mlo.y, mlo.z, mlo.w, mhi.x, mhi.y, mhi.z, mhi.w};
        const float4* p = x4 + (size_t)row0 * F4 + lane;

        float4 v[8];
        #pragma unroll
        for (int j = 0; j < 8; ++j)
            if (m[j] > 0) v[j] = p[j * F4];        // loads batched, uses below
        #pragma unroll
        for (int j = 0; j < 8; ++j)
            if (m[j] > 0) {
                const float4 w = v[j];
                s1.x += w.x; s1.y += w.y; s1.z += w.z; s1.w += w.w;
                s2.x = fmaf(w.x, w.x, s2.x); s2.y = fmaf(w.y, w.y, s2.y);
                s2.z = fmaf(w.z, w.z, s2.z); s2.w = fmaf(w.w, w.w, s2.w);
                cnt += 1.f;
            }
    }

    __shared__ float4 sh1[256];
    __shared__ float4 sh2[256];
    __shared__ float  shc[4];
    sh1[threadIdx.x] = s1;
    sh2[threadIdx.x] = s2;
    if (lane == 0) shc[wv] = cnt;            // cnt is wave-uniform
    __syncthreads();

    if (wv == 0) {
        float4 a = sh1[lane];
        float4 b = sh2[lane];
        #pragma unroll
        for (int w = 1; w < 4; ++w) {
            const float4 c = sh1[w * 64 + lane];
            const float4 d = sh2[w * 64 + lane];
            a.x += c.x; a.y += c.y; a.z += c.z; a.w += c.w;
            b.x += d.x; b.y += d.y; b.z += d.z; b.w += d.w;
        }
        const int f0  = lane * 4;
        const int blk = blockIdx.x;
        pS1[(size_t)(f0 + 0) * nblk + blk] = a.x;
        pS1[(size_t)(f0 + 1) * nblk + blk] = a.y;
        pS1[(size_t)(f0 + 2) * nblk + blk] = a.z;
        pS1[(size_t)(f0 + 3) * nblk + blk] = a.w;
        pS2[(size_t)(f0 + 0) * nblk + blk] = b.x;
        pS2[(size_t)(f0 + 1) * nblk + blk] = b.y;
        pS2[(size_t)(f0 + 2) * nblk + blk] = b.z;
        pS2[(size_t)(f0 + 3) * nblk + blk] = b.w;
        if (lane == 0)
            pCnt[blk] = shc[0] + shc[1] + shc[2] + shc[3];
    }
}

// ---------------------------------------------------------------------------
// Pass 2: fold partials -> scale/shift. One block per feature, 64 threads
// strided over the column (coalesced, column-major), shuffle-reduce.
// ---------------------------------------------------------------------------
__global__ void __launch_bounds__(64) finalize_kernel(
    const float* __restrict__ pS1, const float* __restrict__ pS2,
    const float* __restrict__ pCnt,
    const float* __restrict__ gamma, const float* __restrict__ beta,
    float* __restrict__ scale, float* __restrict__ shift, int nblk)
{
    const int f = blockIdx.x;
    const int t = threadIdx.x;

    const float* c1 = pS1 + (size_t)f * nblk;
    const float* c2 = pS2 + (size_t)f * nblk;

    float s1 = 0.f, s2 = 0.f, c = 0.f;
    for (int b = t; b < nblk; b += 64) {
        s1 += c1[b];
        s2 += c2[b];
        c  += pCnt[b];
    }
    #pragma unroll
    for (int off = 32; off > 0; off >>= 1) {
        s1 += __shfl_down(s1, off);
        s2 += __shfl_down(s2, off);
        c  += __shfl_down(c,  off);
    }
    if (t == 0) {
        const float inv_cnt = 1.f / c;
        const float mean = s1 * inv_cnt;
        const float var  = fmaf(-mean, mean, s2 * inv_cnt);
        const float inv  = rsqrtf(var + EPS);
        const float g    = gamma[f] * inv;
        scale[f] = g;
        shift[f] = fmaf(-mean, g, beta[f]);
    }
}

// ---------------------------------------------------------------------------
// Pass 3: out = mask ? x*scale + shift : x
// Branchless, 8 rows/wave/iter: 8 loads batched, 8 non-temporal stores
// (out is write-once -> don't evict x from L2/L3; norm's x re-read then
// hits the lines reduce warmed).
// ---------------------------------------------------------------------------
__device__ __forceinline__ vfloat4 sel4(int m, const float4 v,
                                        const float4 sc, const float4 sh)
{
    vfloat4 o;
    o.x = (m > 0) ? fmaf(v.x, sc.x, sh.x) : v.x;
    o.y = (m > 0) ? fmaf(v.y, sc.y, sh.y) : v.y;
    o.z = (m > 0) ? fmaf(v.z, sc.z, sh.z) : v.z;
    o.w = (m > 0) ? fmaf(v.w, sc.w, sh.w) : v.w;
    return o;
}

__global__ void __launch_bounds__(256, 4) norm_kernel(
    const float4* __restrict__ x4, const int4* __restrict__ mask4,
    const float4* __restrict__ scale4, const float4* __restrict__ shift4,
    float4* __restrict__ out4)
{
    const int lane = threadIdx.x & 63;
    const int wv   = threadIdx.x >> 6;
    const float4 sc = scale4[lane];
    const float4 sh = shift4[lane];

    vfloat4* __restrict__ outv = reinterpret_cast<vfloat4*>(out4);

    for (int g = blockIdx.x; g < NG; g += gridDim.x) {
        const int row0 = g * 32 + wv * 8;
        const int4 mlo = mask4[(row0 >> 2) + 0];
        const int4 mhi = mask4[(row0 >> 2) + 1];
        const int m[8] = {mlo.x, mlo.y, mlo.z, mlo.w, mhi.x, mhi.y, mhi.z, mhi.w};
        const size_t base = (size_t)row0 * F4 + lane;

        float4 v[8];
        #pragma unroll
        for (int j = 0; j < 8; ++j) v[j] = x4[base + (size_t)j * F4];
        #pragma unroll
        for (int j = 0; j < 8; ++j)
            __builtin_nontemporal_store(sel4(m[j], v[j], sc, sh),
                                        &outv[base + (size_t)j * F4]);
    }
}

// ---------------------------------------------------------------------------
extern "C" void kernel_launch(void* const* d_in, const int* in_sizes, int n_in,
                              void* d_out, int out_size, void* d_ws, size_t ws_size,
                              hipStream_t stream)
{
    const float* x     = (const float*)d_in[0];
    const int*   mask  = (const int*)d_in[1];
    const float* gamma = (const float*)d_in[2];
    const float* beta  = (const float*)d_in[3];
    float* out = (float*)d_out;
    float* ws  = (float*)d_ws;

    // ws layout: pS1[F*nblk] | pS2[F*nblk] | pCnt[nblk] | scale[256] | shift[256]
    // nblk=1024 -> 4 blocks/CU (16 waves/CU) in reduce; ~2.1 MiB ws.
    int nblk = 1024;
    while (nblk > 4 &&
           ((size_t)nblk * F * 2 + nblk + 512) * sizeof(float) > ws_size)
        nblk >>= 1;

    float* pS1   = ws;
    float* pS2   = pS1 + (size_t)F * nblk;
    float* pCnt  = pS2 + (size_t)F * nblk;
    float* scale = pCnt + nblk;
    float* shift = scale + F;

    reduce_kernel<<<nblk, 256, 0, stream>>>(
        (const float4*)x, (const int4*)mask, pS1, pS2, pCnt, nblk);
    finalize_kernel<<<F, 64, 0, stream>>>(
        pS1, pS2, pCnt, gamma, beta, scale, shift, nblk);
    norm_kernel<<<1024, 256, 0, stream>>>(
        (const float4*)x, (const int4*)mask, (const float4*)scale,
        (const float4*)shift, (float4*)out);
}